// Round 1
// baseline (164.186 us; speedup 1.0000x reference)
//
#include <hip/hip_runtime.h>

#define N_TOK 2048
#define DIM   512
#define NEXP  16
#define HID   2048
#define NSLOT (N_TOK*2)

typedef __attribute__((ext_vector_type(8))) short short8;
typedef __attribute__((ext_vector_type(4))) float floatx4;

__device__ __forceinline__ ushort f2bf(float f) {
    union { float f; unsigned u; } c; c.f = f;
    unsigned u = c.u;
    unsigned r = (u + 0x7fffu + ((u >> 16) & 1u)) >> 16;
    return (ushort)r;
}

// ---------------- Router: RMSNorm + logits + top2 softmax ----------------
__global__ __launch_bounds__(64)
void router_kernel(const float* __restrict__ x, const float* __restrict__ w_norm,
                   const float* __restrict__ Wr, const float* __restrict__ br,
                   ushort* __restrict__ xn, int* __restrict__ cnt,
                   int4* __restrict__ rec_ei, float2* __restrict__ rec_w)
{
    const int t = blockIdx.x;
    const int lane = threadIdx.x;
    const float* xr = x + (size_t)t * DIM;

    float v[8];
    float ss = 0.f;
#pragma unroll
    for (int i = 0; i < 8; i++) { v[i] = xr[lane + i * 64]; ss += v[i] * v[i]; }
#pragma unroll
    for (int m = 32; m >= 1; m >>= 1) ss += __shfl_xor(ss, m, 64);
    const float rinv = 1.f / sqrtf(ss / (float)DIM + 1e-10f);

    float part[16];
#pragma unroll
    for (int e = 0; e < 16; e++) part[e] = 0.f;

#pragma unroll
    for (int i = 0; i < 8; i++) {
        const int d = lane + i * 64;
        const float xnv = w_norm[d] * v[i] * rinv;
        xn[(size_t)t * DIM + d] = f2bf(xnv);
        const float4* wr4 = (const float4*)(Wr + (size_t)d * 16);
#pragma unroll
        for (int q = 0; q < 4; q++) {
            float4 w4 = wr4[q];
            part[q*4+0] += xnv * w4.x;
            part[q*4+1] += xnv * w4.y;
            part[q*4+2] += xnv * w4.z;
            part[q*4+3] += xnv * w4.w;
        }
    }
#pragma unroll
    for (int e = 0; e < 16; e++) {
        float s = part[e];
#pragma unroll
        for (int m = 32; m >= 1; m >>= 1) s += __shfl_xor(s, m, 64);
        part[e] = s + br[e];
    }

    if (lane == 0) {
        int i0 = 0; float m0 = part[0];
#pragma unroll
        for (int e = 1; e < 16; e++) if (part[e] > m0) { m0 = part[e]; i0 = e; }
        int i1 = -1; float m1 = -1e30f;
#pragma unroll
        for (int e = 0; e < 16; e++) if (e != i0 && part[e] > m1) { m1 = part[e]; i1 = e; }
        const float e1v = expf(m1 - m0);
        const float w0 = 1.f / (1.f + e1v);
        const float w1 = e1v / (1.f + e1v);
        const int r0 = atomicAdd(&cnt[i0], 1);
        const int r1 = atomicAdd(&cnt[i1], 1);
        rec_ei[t] = make_int4(i0, i1, r0, r1);
        rec_w[t] = make_float2(w0, w1);
    }
}

__global__ void scan_kernel(const int* __restrict__ cnt, int* __restrict__ off)
{
    if (threadIdx.x == 0) {
        int a = 0;
        for (int e = 0; e < NEXP; e++) { off[e] = a; a += cnt[e]; }
        off[NEXP] = a;
    }
}

__global__ void fill_kernel(const int4* __restrict__ rec_ei, const int* __restrict__ off,
                            int* __restrict__ tok_of_slot, int2* __restrict__ rec_slot)
{
    const int t = blockIdx.x * blockDim.x + threadIdx.x;
    if (t >= N_TOK) return;
    int4 r = rec_ei[t];
    const int s0 = off[r.x] + r.z;
    const int s1 = off[r.y] + r.w;
    tok_of_slot[s0] = t;
    tok_of_slot[s1] = t;
    rec_slot[t] = make_int2(s0, s1);
}

// ---------------- Expert GEMM (gathered rows, bf16 MFMA) ----------------
// MODE 0: h = silu(xn @ W1 + b1) -> bf16 h_buf     (K=512,  Nn=2048, gather via tok_of_slot)
// MODE 1: y = h @ W2             -> f32  y_buf     (K=2048, Nn=512,  rows are slots)
#define BM 128
#define BN 64
#define BK 64
#define SA 72   // padded LDS row stride (elems): 144B = 9*16B -> aligned b128, 2-way max conflict

template<int MODE>
__global__ __launch_bounds__(256)
void gemm_expert(const ushort* __restrict__ A, int a_stride,
                 const float* __restrict__ W, const float* __restrict__ bias,
                 int K, int Nn,
                 const int* __restrict__ cnt, const int* __restrict__ off,
                 const int* __restrict__ tok_of_slot,
                 ushort* __restrict__ hout, float* __restrict__ yout)
{
    const int e = blockIdx.y >> 4;
    const int mt = blockIdx.y & 15;
    const int count = cnt[e];
    if (mt * BM >= count) return;
    const int base = off[e];
    const int rows = min(BM, count - mt * BM);
    const int n0 = blockIdx.x * BN;

    __shared__ __align__(16) ushort As[BM][SA];
    __shared__ __align__(16) ushort Bs[BN][SA];
    __shared__ int toks[BM];

    const int tid = threadIdx.x;
    if (tid < BM) {
        const int r = tid < rows ? tid : rows - 1;
        const int slot = base + mt * BM + r;
        toks[tid] = (MODE == 0) ? tok_of_slot[slot] : slot;
    }
    __syncthreads();

    const int lane = tid & 63;
    const int wid = tid >> 6;
    const int wm = wid >> 1, wn = wid & 1;
    const int fr = lane & 15, fg = lane >> 4;

    floatx4 acc[4][2];
#pragma unroll
    for (int mi = 0; mi < 4; mi++)
#pragma unroll
        for (int ni = 0; ni < 2; ni++)
#pragma unroll
            for (int r = 0; r < 4; r++) acc[mi][ni][r] = 0.f;

    const int a_kcol = (tid & 7) * 8;
    const int a_row0 = tid >> 3;
    const int b_n = tid & 63;
    const int b_kq = (tid >> 6) * 4;

    for (int k0 = 0; k0 < K; k0 += BK) {
        // stage A tile (gathered bf16 rows)
#pragma unroll
        for (int p = 0; p < 4; p++) {
            const int row = p * 32 + a_row0;
            const uint4 v = *(const uint4*)(A + (size_t)toks[row] * a_stride + k0 + a_kcol);
            *(uint4*)&As[row][a_kcol] = v;
        }
        // stage B tile: W[e][k][n] f32, coalesced along n, cvt->bf16, k-contiguous writes
        const float* Wp = W + ((size_t)e * K + k0) * Nn + n0 + b_n;
#pragma unroll
        for (int p = 0; p < 4; p++) {
            const int kk = p * 16 + b_kq;
            const float f0 = Wp[(size_t)(kk + 0) * Nn];
            const float f1 = Wp[(size_t)(kk + 1) * Nn];
            const float f2 = Wp[(size_t)(kk + 2) * Nn];
            const float f3 = Wp[(size_t)(kk + 3) * Nn];
            ushort4 bq;
            bq.x = f2bf(f0); bq.y = f2bf(f1); bq.z = f2bf(f2); bq.w = f2bf(f3);
            *(ushort4*)&Bs[b_n][kk] = bq;
        }
        __syncthreads();
#pragma unroll
        for (int kh = 0; kh < 2; kh++) {
            const int kk = kh * 32 + fg * 8;
            short8 af[4], bfr[2];
#pragma unroll
            for (int mi = 0; mi < 4; mi++)
                af[mi] = *(const short8*)&As[wm * 64 + mi * 16 + fr][kk];
#pragma unroll
            for (int ni = 0; ni < 2; ni++)
                bfr[ni] = *(const short8*)&Bs[wn * 32 + ni * 16 + fr][kk];
#pragma unroll
            for (int mi = 0; mi < 4; mi++)
#pragma unroll
                for (int ni = 0; ni < 2; ni++)
                    acc[mi][ni] = __builtin_amdgcn_mfma_f32_16x16x32_bf16(af[mi], bfr[ni], acc[mi][ni], 0, 0, 0);
        }
        __syncthreads();
    }

    // epilogue
    const int cn = fr, rq = fg * 4;
#pragma unroll
    for (int ni = 0; ni < 2; ni++) {
        const int gn = n0 + wn * 32 + ni * 16 + cn;
        const float bv = (MODE == 0) ? bias[e * Nn + gn] : 0.f;
#pragma unroll
        for (int mi = 0; mi < 4; mi++) {
#pragma unroll
            for (int r = 0; r < 4; r++) {
                const int lm = wm * 64 + mi * 16 + rq + r;
                if (lm < rows) {
                    const int slot = base + mt * BM + lm;
                    float v = acc[mi][ni][r];
                    if (MODE == 0) {
                        v += bv;
                        v = v / (1.f + expf(-v));   // silu
                        hout[(size_t)slot * Nn + gn] = f2bf(v);
                    } else {
                        yout[(size_t)slot * Nn + gn] = v;
                    }
                }
            }
        }
    }
}

// ---------------- Final gather: out = x + w0*(y0+b2[e0]) + w1*(y1+b2[e1]) ----------------
__global__ __launch_bounds__(128)
void gather_kernel(const float* __restrict__ x, const float* __restrict__ y,
                   const float* __restrict__ b2,
                   const int4* __restrict__ rec_ei, const float2* __restrict__ rec_w,
                   const int2* __restrict__ rec_slot, float* __restrict__ out)
{
    const int t = blockIdx.x;
    const int d4 = threadIdx.x * 4;
    const int4 ei = rec_ei[t];
    const float2 w = rec_w[t];
    const int2 sl = rec_slot[t];
    const float4 xv  = *(const float4*)(x  + (size_t)t * DIM + d4);
    const float4 y0  = *(const float4*)(y  + (size_t)sl.x * DIM + d4);
    const float4 y1  = *(const float4*)(y  + (size_t)sl.y * DIM + d4);
    const float4 b0  = *(const float4*)(b2 + (size_t)ei.x * DIM + d4);
    const float4 b1v = *(const float4*)(b2 + (size_t)ei.y * DIM + d4);
    float4 o;
    o.x = xv.x + w.x * (y0.x + b0.x) + w.y * (y1.x + b1v.x);
    o.y = xv.y + w.x * (y0.y + b0.y) + w.y * (y1.y + b1v.y);
    o.z = xv.z + w.x * (y0.z + b0.z) + w.y * (y1.z + b1v.z);
    o.w = xv.w + w.x * (y0.w + b0.w) + w.y * (y1.w + b1v.w);
    *(float4*)(out + (size_t)t * DIM + d4) = o;
}

extern "C" void kernel_launch(void* const* d_in, const int* in_sizes, int n_in,
                              void* d_out, int out_size, void* d_ws, size_t ws_size,
                              hipStream_t stream)
{
    const float* x  = (const float*)d_in[0];
    const float* wn = (const float*)d_in[1];
    const float* Wr = (const float*)d_in[2];
    const float* br = (const float*)d_in[3];
    const float* W1 = (const float*)d_in[4];
    const float* b1 = (const float*)d_in[5];
    const float* W2 = (const float*)d_in[6];
    const float* b2 = (const float*)d_in[7];
    float* out = (float*)d_out;

    char* ws = (char*)d_ws;
    ushort* xn    = (ushort*)(ws);                         // 2 MB
    ushort* h_buf = (ushort*)(ws + (2u  << 20));           // 16 MB
    float*  y_buf = (float*) (ws + (18u << 20));           // 8 MB
    char* p = ws + (26u << 20);
    int*    cnt         = (int*)p;    p += 256;
    int*    off         = (int*)p;    p += 256;
    int4*   rec_ei      = (int4*)p;   p += N_TOK * 16;
    float2* rec_w       = (float2*)p; p += N_TOK * 8;
    int2*   rec_slot    = (int2*)p;   p += N_TOK * 8;
    int*    tok_of_slot = (int*)p;    p += NSLOT * 4;

    hipMemsetAsync(cnt, 0, NEXP * sizeof(int), stream);
    router_kernel<<<N_TOK, 64, 0, stream>>>(x, wn, Wr, br, xn, cnt, rec_ei, rec_w);
    scan_kernel<<<1, 64, 0, stream>>>(cnt, off);
    fill_kernel<<<N_TOK / 256, 256, 0, stream>>>(rec_ei, off, tok_of_slot, rec_slot);

    // GEMM1: h = silu(xn @ W1 + b1), M=slots, K=512, N=2048
    gemm_expert<0><<<dim3(HID / BN, NEXP * 16), 256, 0, stream>>>(
        xn, DIM, W1, b1, DIM, HID, cnt, off, tok_of_slot, h_buf, nullptr);
    // GEMM2: y = h @ W2, M=slots, K=2048, N=512
    gemm_expert<1><<<dim3(DIM / BN, NEXP * 16), 256, 0, stream>>>(
        h_buf, HID, W2, nullptr, HID, DIM, cnt, off, nullptr, nullptr, y_buf);

    gather_kernel<<<N_TOK, 128, 0, stream>>>(x, y_buf, b2, rec_ei, rec_w, rec_slot, out);
}